// Round 4
// baseline (8348.920 us; speedup 1.0000x reference)
//
#include <hip/hip_runtime.h>
#include <hip/hip_bf16.h>

// ---------------------------------------------------------------------------
// AJ-RNN forward (B=128,T=256,D=64,H=512), persistent-kernel version.
// One kernel runs all 256 timesteps; 64 blocks (1/CU), block j owns h-cols
// [8j,8j+8) of both layers (all 4 gates, gate-interleaved weight packing).
// Weights + cell state LDS-resident; h1/h2 ping-pong in global; 3 device-
// scope counter barriers per step (768 total).
// ---------------------------------------------------------------------------

typedef __bf16  v8bf  __attribute__((ext_vector_type(8)));
typedef float   f32x4 __attribute__((ext_vector_type(4)));

constexpr int B_ = 128, T_ = 256, D_ = 64, H_ = 512;

// workspace layout (bytes)
constexpr size_t OFF_WP1 = 0;        // gate-interleaved packed [k0;r0]: 128ct*18kc*512*2 = 2359296
constexpr size_t OFF_WP2 = 2359296;  // gate-interleaved packed [k1;r1]: 128*32*512*2     = 4194304
constexpr size_t OFF_WPP = 6553600;  // plain packed W: 4ct*16kc*512*2                    =   65536
constexpr size_t OFF_H1A = 6619136;  // h1 ping bf16 131072
constexpr size_t OFF_H1B = 6750208;  // h1 pong
constexpr size_t OFF_H2A = 6881280;  // h2 ping
constexpr size_t OFF_H2B = 7012352;  // h2 pong
constexpr size_t OFF_CUR = 7143424;  // cur bf16 [128][64] = 16384
constexpr size_t OFF_CTR = 7159808;  // barrier counter (256 B slot)
// total ~7.16 MB (round-3 used 7.67 MB successfully)

__device__ __forceinline__ v8bf ldv(const __hip_bfloat16* p) {
  return *reinterpret_cast<const v8bf*>(p);
}
__device__ __forceinline__ float sigf(float x) { return 1.0f / (1.0f + __expf(-x)); }
__device__ __forceinline__ float tanhfast(float x) {
  x = fminf(15.0f, fmaxf(-15.0f, x));
  float e = __expf(-2.0f * x);
  return (1.0f - e) / (1.0f + e);
}

// device-scope barrier: every block calls with the same monotonically
// increasing target (64 * phase). Release on arrive, acquire on observe.
__device__ __forceinline__ void gbar(unsigned* ctr, unsigned target) {
  __syncthreads();
  if (threadIdx.x == 0) {
    __threadfence();
    __hip_atomic_fetch_add(ctr, 1u, __ATOMIC_RELEASE, __HIP_MEMORY_SCOPE_AGENT);
    while (__hip_atomic_load(ctr, __ATOMIC_ACQUIRE, __HIP_MEMORY_SCOPE_AGENT) < target)
      __builtin_amdgcn_s_sleep(1);
    __threadfence();
  }
  __syncthreads();
}

// ---------------------------------------------------------------------------
// Gate-interleaved fragment packer for recurrent weights.
// dst[((ct*nkc + kc)*64 + L)*8 + e] = Wcat[kc*32 + (L>>4)*8 + e][col(ct,L)]
// col(ct,L): j = ct>>1, half = ct&1, c16 = L&15,
//            gate = half*2 + (c16>>3), hcol = 8j + (c16&7), col = gate*512+hcol
// So tile (2j+0) = [i|f] and tile (2j+1) = [g|o] for h-cols [8j,8j+8).
// ---------------------------------------------------------------------------
__global__ __launch_bounds__(256) void pack_gi(
    const float* __restrict__ kp, const float* __restrict__ rp,
    int krows, int nkc, __hip_bfloat16* __restrict__ out) {
  int tid = blockIdx.x * 256 + threadIdx.x;
  int total = 128 * nkc * 64;
  if (tid >= total) return;
  int L  = tid & 63;
  int kc = (tid >> 6) % nkc;
  int ct = tid / (64 * nkc);
  int c16  = L & 15;
  int gate = (ct & 1) * 2 + (c16 >> 3);
  int hcol = 8 * (ct >> 1) + (c16 & 7);
  int n  = gate * 512 + hcol;
  int kb = kc * 32 + (L >> 4) * 8;
  __hip_bfloat16* dst = out + (size_t)tid * 8;
#pragma unroll
  for (int e = 0; e < 8; ++e) {
    int kk = kb + e;
    float v = (kk < krows) ? kp[kk * 2048 + n] : rp[(kk - krows) * 2048 + n];
    dst[e] = __float2bfloat16(v);
  }
}

// plain packer for the imputation weight W (512x64), nct=4, nkc=16
__global__ __launch_bounds__(256) void pack_plain(
    const float* __restrict__ kp, __hip_bfloat16* __restrict__ out) {
  int tid = blockIdx.x * 256 + threadIdx.x;
  if (tid >= 4 * 16 * 64) return;
  int L  = tid & 63;
  int kc = (tid >> 6) % 16;
  int ct = tid / (64 * 16);
  int n  = ct * 16 + (L & 15);
  int kb = kc * 32 + (L >> 4) * 8;
  __hip_bfloat16* dst = out + (size_t)tid * 8;
#pragma unroll
  for (int e = 0; e < 8; ++e) dst[e] = __float2bfloat16(kp[(kb + e) * 64 + n]);
}

__global__ __launch_bounds__(256) void init_misc(
    __hip_bfloat16* __restrict__ h1a, __hip_bfloat16* __restrict__ h2a,
    unsigned* __restrict__ ctr) {
  int idx = blockIdx.x * 256 + threadIdx.x;   // 65536
  h1a[idx] = __float2bfloat16(0.0f);
  h2a[idx] = __float2bfloat16(0.0f);
  if (idx == 0) *ctr = 0u;
}

// ---------------------------------------------------------------------------
__global__ __launch_bounds__(256) void rnn_persist(
    const float* __restrict__ x,
    const __hip_bfloat16* __restrict__ W1g,
    const __hip_bfloat16* __restrict__ W2g,
    const __hip_bfloat16* __restrict__ WpPg,
    const float* __restrict__ b0,
    const float* __restrict__ b1,
    const float* __restrict__ biasD,
    __hip_bfloat16* __restrict__ curg,
    __hip_bfloat16* __restrict__ h1a, __hip_bfloat16* __restrict__ h1b,
    __hip_bfloat16* __restrict__ h2a, __hip_bfloat16* __restrict__ h2b,
    unsigned* ctr,
    float* __restrict__ outp, float* __restrict__ lastp) {
  __shared__ __hip_bfloat16 lW1[2][18][64 * 8];   // 36864 B
  __shared__ __hip_bfloat16 lW2[2][32][64 * 8];   // 65536 B
  __shared__ float zb[4][2][2][16][16];           // 16384 B
  __shared__ float predpart[4][16][16];           //  4096 B
  __shared__ float lc1[1024];                     //  4096 B
  __shared__ float lc2[1024];                     //  4096 B
  __shared__ float lb0[4][8], lb1[4][8];          //   256 B

  const int j   = blockIdx.x;        // owns h-cols [8j, 8j+8)
  const int tid = threadIdx.x;
  const int w = tid >> 6, L = tid & 63, m = L & 15, q = L >> 4;

  // ---- one-time: weight slices -> LDS, biases, zero cell state ----
  {
    const __hip_bfloat16* s1 = W1g + (size_t)(2 * j) * 18 * 512;
    __hip_bfloat16* d1 = &lW1[0][0][0];
    for (int i = tid * 8; i < 2 * 18 * 512; i += 256 * 8)
      *reinterpret_cast<v8bf*>(d1 + i) = ldv(s1 + i);
    const __hip_bfloat16* s2 = W2g + (size_t)(2 * j) * 32 * 512;
    __hip_bfloat16* d2 = &lW2[0][0][0];
    for (int i = tid * 8; i < 2 * 32 * 512; i += 256 * 8)
      *reinterpret_cast<v8bf*>(d2 + i) = ldv(s2 + i);
  }
  if (tid < 32) {
    int g = tid >> 3, c = tid & 7;
    lb0[g][c] = b0[g * 512 + 8 * j + c];
    lb1[g][c] = b1[g * 512 + 8 * j + c];
  }
  for (int i = tid; i < 1024; i += 256) { lc1[i] = 0.f; lc2[i] = 0.f; }
  __syncthreads();

  const int pmt = j >> 2, pnt = j & 3;     // pred job (blocks 0..31)
  const int R0 = pmt * 16, C0 = pnt * 16;
  unsigned ph = 0;

  for (int t = 0; t < T_; ++t) {
    const __hip_bfloat16* h1r = (t & 1) ? h1b : h1a;
    __hip_bfloat16*       h1w = (t & 1) ? h1a : h1b;
    const __hip_bfloat16* h2r = (t & 1) ? h2b : h2a;
    __hip_bfloat16*       h2w = (t & 1) ? h2a : h2b;

    // ---------------- Phase P: pred tile + cur (blocks 0..31) -------------
    if (j < 32) {
      if (t > 0) {
        f32x4 acc = {0.f, 0.f, 0.f, 0.f};
#pragma unroll
        for (int kk = 0; kk < 4; ++kk) {
          int kc = w * 4 + kk;
          v8bf a  = ldv(h2r + (size_t)(R0 + m) * H_ + kc * 32 + q * 8);
          v8bf bb = ldv(WpPg + ((size_t)(pnt * 16 + kc) * 64 + L) * 8);
          acc = __builtin_amdgcn_mfma_f32_16x16x32_bf16(a, bb, acc, 0, 0, 0);
        }
#pragma unroll
        for (int r = 0; r < 4; ++r) predpart[w][q * 4 + r][m] = acc[r];
      }
      __syncthreads();
      {
        int row = tid >> 4, col = tid & 15;
        float xv = x[((size_t)(R0 + row) * T_ + t) * D_ + C0 + col];
        float cv = xv;
        if (t > 0) {
          float pv = predpart[0][row][col] + predpart[1][row][col] +
                     predpart[2][row][col] + predpart[3][row][col] +
                     biasD[C0 + col];
          outp[((size_t)(R0 + row) * (T_ - 1) + (t - 1)) * D_ + C0 + col] = pv;
          if (xv == 128.0f) cv = pv;
        }
        curg[(R0 + row) * D_ + C0 + col] = __float2bfloat16(cv);
      }
    }
    gbar(ctr, 64u * (++ph));

    // ---------------- Phase L1: z1 = [cur | h1_{t-1}] @ W1 ----------------
    {
      f32x4 acc[2][2] = {{{0.f,0.f,0.f,0.f},{0.f,0.f,0.f,0.f}},
                         {{0.f,0.f,0.f,0.f},{0.f,0.f,0.f,0.f}}};
      const int mt0 = 2 * w;
#pragma unroll
      for (int kc = 0; kc < 18; ++kc) {
        v8bf bf0 = ldv(&lW1[0][kc][L * 8]);
        v8bf bf1 = ldv(&lW1[1][kc][L * 8]);
#pragma unroll
        for (int u = 0; u < 2; ++u) {
          int gr = (mt0 + u) * 16 + m;
          v8bf a = (kc < 2) ? ldv(curg + gr * D_ + kc * 32 + q * 8)
                            : ldv(h1r + (size_t)gr * H_ + (kc - 2) * 32 + q * 8);
          acc[u][0] = __builtin_amdgcn_mfma_f32_16x16x32_bf16(a, bf0, acc[u][0], 0, 0, 0);
          acc[u][1] = __builtin_amdgcn_mfma_f32_16x16x32_bf16(a, bf1, acc[u][1], 0, 0, 0);
        }
      }
#pragma unroll
      for (int u = 0; u < 2; ++u)
#pragma unroll
        for (int s = 0; s < 2; ++s)
#pragma unroll
          for (int r = 0; r < 4; ++r) zb[w][u][s][q * 4 + r][m] = acc[u][s][r];
    }
    __syncthreads();
    {
#pragma unroll
      for (int it = 0; it < 4; ++it) {
        int idx = tid + 256 * it;          // = gr*8 + hcol
        int hcol = idx & 7, gr = idx >> 3;
        int mt = gr >> 4, rl = gr & 15, wv = mt >> 1, u = mt & 1;
        float iv = zb[wv][u][0][rl][hcol]     + lb0[0][hcol];
        float fv = zb[wv][u][0][rl][hcol + 8] + lb0[1][hcol];
        float gv = zb[wv][u][1][rl][hcol]     + lb0[2][hcol];
        float ov = zb[wv][u][1][rl][hcol + 8] + lb0[3][hcol];
        float ig = sigf(iv), fg = sigf(fv), gg = tanhfast(gv), og = sigf(ov);
        float cn = fg * lc1[idx] + ig * gg;
        float hn = og * tanhfast(cn);
        lc1[idx] = cn;
        h1w[(size_t)gr * H_ + 8 * j + hcol] = __float2bfloat16(hn);
      }
    }
    gbar(ctr, 64u * (++ph));

    // ---------------- Phase L2: z2 = [h1_t | h2_{t-1}] @ W2 ---------------
    {
      f32x4 acc[2][2] = {{{0.f,0.f,0.f,0.f},{0.f,0.f,0.f,0.f}},
                         {{0.f,0.f,0.f,0.f},{0.f,0.f,0.f,0.f}}};
      const int mt0 = 2 * w;
#pragma unroll
      for (int kc = 0; kc < 32; ++kc) {
        v8bf bf0 = ldv(&lW2[0][kc][L * 8]);
        v8bf bf1 = ldv(&lW2[1][kc][L * 8]);
#pragma unroll
        for (int u = 0; u < 2; ++u) {
          int gr = (mt0 + u) * 16 + m;
          v8bf a = (kc < 16) ? ldv(h1w + (size_t)gr * H_ + kc * 32 + q * 8)
                             : ldv(h2r + (size_t)gr * H_ + (kc - 16) * 32 + q * 8);
          acc[u][0] = __builtin_amdgcn_mfma_f32_16x16x32_bf16(a, bf0, acc[u][0], 0, 0, 0);
          acc[u][1] = __builtin_amdgcn_mfma_f32_16x16x32_bf16(a, bf1, acc[u][1], 0, 0, 0);
        }
      }
#pragma unroll
      for (int u = 0; u < 2; ++u)
#pragma unroll
        for (int s = 0; s < 2; ++s)
#pragma unroll
          for (int r = 0; r < 4; ++r) zb[w][u][s][q * 4 + r][m] = acc[u][s][r];
    }
    __syncthreads();
    {
#pragma unroll
      for (int it = 0; it < 4; ++it) {
        int idx = tid + 256 * it;
        int hcol = idx & 7, gr = idx >> 3;
        int mt = gr >> 4, rl = gr & 15, wv = mt >> 1, u = mt & 1;
        float iv = zb[wv][u][0][rl][hcol]     + lb1[0][hcol];
        float fv = zb[wv][u][0][rl][hcol + 8] + lb1[1][hcol];
        float gv = zb[wv][u][1][rl][hcol]     + lb1[2][hcol];
        float ov = zb[wv][u][1][rl][hcol + 8] + lb1[3][hcol];
        float ig = sigf(iv), fg = sigf(fv), gg = tanhfast(gv), og = sigf(ov);
        float cn = fg * lc2[idx] + ig * gg;
        float hn = og * tanhfast(cn);
        lc2[idx] = cn;
        h2w[(size_t)gr * H_ + 8 * j + hcol] = __float2bfloat16(hn);
        if (t == T_ - 1) lastp[(size_t)gr * H_ + 8 * j + hcol] = hn;
      }
    }
    gbar(ctr, 64u * (++ph));
  }
}

// ---------------------------------------------------------------------------
extern "C" void kernel_launch(void* const* d_in, const int* in_sizes, int n_in,
                              void* d_out, int out_size, void* d_ws, size_t ws_size,
                              hipStream_t stream) {
  const float* x    = (const float*)d_in[0];
  const float* k0   = (const float*)d_in[1];
  const float* r0   = (const float*)d_in[2];
  const float* b0   = (const float*)d_in[3];
  const float* k1   = (const float*)d_in[4];
  const float* r1   = (const float*)d_in[5];
  const float* b1   = (const float*)d_in[6];
  const float* W    = (const float*)d_in[7];
  const float* bias = (const float*)d_in[8];

  char* ws = (char*)d_ws;
  __hip_bfloat16* Wp1 = (__hip_bfloat16*)(ws + OFF_WP1);
  __hip_bfloat16* Wp2 = (__hip_bfloat16*)(ws + OFF_WP2);
  __hip_bfloat16* WpP = (__hip_bfloat16*)(ws + OFF_WPP);
  __hip_bfloat16* h1a = (__hip_bfloat16*)(ws + OFF_H1A);
  __hip_bfloat16* h1b = (__hip_bfloat16*)(ws + OFF_H1B);
  __hip_bfloat16* h2a = (__hip_bfloat16*)(ws + OFF_H2A);
  __hip_bfloat16* h2b = (__hip_bfloat16*)(ws + OFF_H2B);
  __hip_bfloat16* cur = (__hip_bfloat16*)(ws + OFF_CUR);
  unsigned*       ctr = (unsigned*)(ws + OFF_CTR);

  pack_gi<<<576, 256, 0, stream>>>(k0, r0, 64, 18, Wp1);
  pack_gi<<<1024, 256, 0, stream>>>(k1, r1, 512, 32, Wp2);
  pack_plain<<<16, 256, 0, stream>>>(W, WpP);
  init_misc<<<256, 256, 0, stream>>>(h1a, h2a, ctr);

  float* outp = (float*)d_out;
  float* last = outp + (size_t)B_ * (T_ - 1) * D_;

  rnn_persist<<<64, 256, 0, stream>>>(x, Wp1, Wp2, WpP, b0, b1, bias,
                                      cur, h1a, h1b, h2a, h2b, ctr, outp, last);
}